// Round 3
// baseline (967.729 us; speedup 1.0000x reference)
//
#include <hip/hip_runtime.h>

#define N_NODES 50000
#define N_EDGES 800000
#define IN_C 128
#define HID 32
#define HC 128
#define OUT_C 16
#define NGRAPH 64
#define NPB 8    // nodes per block in node GEMM
#define PNB 125  // nodes per block in pool (50000/125 = 400 blocks)
#define TPB 4    // targets per block in edge attn (4 waves of 64)

// ---------------- CSR build ----------------
__global__ void k_hist(const int* __restrict__ tgt, int* __restrict__ deg) {
  int i = blockIdx.x * blockDim.x + threadIdx.x;
  if (i < N_EDGES) atomicAdd(&deg[tgt[i]], 1);
}

// single-block scan, shfl-based
__global__ __launch_bounds__(1024) void k_scan(const int* __restrict__ deg,
                                               int* __restrict__ offs,
                                               int* __restrict__ cursor) {
  __shared__ int wsum[16];
  __shared__ int carry_s;
  int lane = threadIdx.x & 63, wid = threadIdx.x >> 6;
  if (threadIdx.x == 0) { carry_s = 0; offs[0] = 0; }
  __syncthreads();
  for (int base = 0; base < N_NODES; base += 1024) {
    int i = base + threadIdx.x;
    int v = (i < N_NODES) ? deg[i] : 0;
    int x = v;
#pragma unroll
    for (int off = 1; off < 64; off <<= 1) {
      int t = __shfl_up(x, off, 64);
      if (lane >= off) x += t;
    }
    if (lane == 63) wsum[wid] = x;
    __syncthreads();
    if (wid == 0 && lane < 16) {
      int s = wsum[lane];
#pragma unroll
      for (int off = 1; off < 16; off <<= 1) {
        int t = __shfl_up(s, off, 64);
        if (lane >= off) s += t;
      }
      wsum[lane] = s;
    }
    __syncthreads();
    int add = (wid > 0 ? wsum[wid - 1] : 0) + carry_s;
    int incl = x + add;
    if (i < N_NODES) { offs[i + 1] = incl; cursor[i] = incl - v; }
    __syncthreads();
    if (threadIdx.x == 1023) carry_s = incl;
    __syncthreads();
  }
}

__global__ void k_scatter(const int* __restrict__ src, const int* __restrict__ tgt,
                          int* __restrict__ cursor, int* __restrict__ srcs,
                          int* __restrict__ eids) {
  int i = blockIdx.x * blockDim.x + threadIdx.x;
  if (i < N_EDGES) {
    int pos = atomicAdd(&cursor[tgt[i]], 1);
    srcs[pos] = src[i];
    eids[pos] = i;
  }
}

// ---------------- node GEMM: qn/kn/vn/sk = x@W+b, plus p = f(qn, we) ----------------
__global__ __launch_bounds__(128) void k_node_gemm(
    const float* __restrict__ xin,
    const float* __restrict__ wq, const float* __restrict__ bq,
    const float* __restrict__ wk, const float* __restrict__ bk,
    const float* __restrict__ wv, const float* __restrict__ bv,
    const float* __restrict__ ws, const float* __restrict__ bs,
    const float* __restrict__ we,
    float* __restrict__ qn, float* __restrict__ kn, float* __restrict__ vn,
    float* __restrict__ sk, float* __restrict__ p) {
  int c = threadIdx.x;           // output column 0..127
  int n0 = blockIdx.x * NPB;
  float aq[NPB], ak[NPB], av[NPB], as_[NPB];
#pragma unroll
  for (int i = 0; i < NPB; ++i) { aq[i] = 0.f; ak[i] = 0.f; av[i] = 0.f; as_[i] = 0.f; }
  for (int d = 0; d < IN_C; ++d) {
    float wqv = wq[d * HC + c];
    float wkv = wk[d * HC + c];
    float wvv = wv[d * HC + c];
    float wsv = ws[d * HC + c];
#pragma unroll
    for (int i = 0; i < NPB; ++i) {
      float xv = xin[(n0 + i) * IN_C + d];   // wave-uniform -> scalar load
      aq[i] = fmaf(xv, wqv, aq[i]);
      ak[i] = fmaf(xv, wkv, ak[i]);
      av[i] = fmaf(xv, wvv, av[i]);
      as_[i] = fmaf(xv, wsv, as_[i]);
    }
  }
  __shared__ float qs[NPB][HC];
#pragma unroll
  for (int i = 0; i < NPB; ++i) {
    int n = n0 + i;
    float q = aq[i] + bq[c];
    qn[n * HC + c] = q;
    qs[i][c] = q;
    kn[n * HC + c] = ak[i] + bk[c];
    vn[n * HC + c] = av[i] + bv[c];
    sk[n * HC + c] = as_[i] + bs[c];
  }
  __syncthreads();
  int hb = (c >> 5) << 5;   // head base of column c
  int j = c & 31;
  float acc[NPB];
#pragma unroll
  for (int i = 0; i < NPB; ++i) acc[i] = 0.f;
  for (int d = 0; d < 32; ++d) {
    float wev = we[j * HC + hb + d];
#pragma unroll
    for (int i = 0; i < NPB; ++i) acc[i] = fmaf(qs[i][hb + d], wev, acc[i]);
  }
#pragma unroll
  for (int i = 0; i < NPB; ++i) p[(n0 + i) * HC + c] = acc[i];
}

// ---------------- edge attention ----------------
// 4 waves/block, one target per wave. Lane owns feature pair (2*lane, 2*lane+1);
// head = lane>>4 lives in a contiguous 16-lane group -> 4-shuffle allreduce.
__global__ __launch_bounds__(256) void k_edge_attn(
    const int* __restrict__ offs, const int* __restrict__ srcs,
    const int* __restrict__ eids, const float* __restrict__ ea,
    const float* __restrict__ qn, const float* __restrict__ kn,
    const float* __restrict__ vn, const float* __restrict__ sk,
    const float* __restrict__ p, const float* __restrict__ we,
    float* __restrict__ out) {
  int lane = threadIdx.x & 63;
  int wv_ = threadIdx.x >> 6;
  int t = blockIdx.x * TPB + wv_;
  int f = 2 * lane;                 // feature pair base
  int h = lane >> 4;                // head of this lane
  int dh = 2 * (lane & 15);         // dim-pair within head (0..30)
  int e0 = offs[t], e1 = offs[t + 1];
  float2 q2 = *(const float2*)&qn[t * HC + f];
  float2 p2 = *(const float2*)&p[t * HC + f];
  const float inv_sqrt = 0.17677669529663687f;  // 1/sqrt(32)
  float m = -1e30f, den = 0.f;
  float2 acc = {0.f, 0.f}, tac = {0.f, 0.f};
  for (int base = e0; base < e1; base += 64) {
    int li = base + lane;
    int sl = (li < e1) ? srcs[li] : 0;
    int el = (li < e1) ? eids[li] : 0;
    int cnt = min(64, e1 - base);
    for (int j = 0; j < cnt; ++j) {
      int s = __shfl(sl, j, 64);
      int eid = __shfl(el, j, 64);
      float2 ea2 = *(const float2*)&ea[eid * HID + dh];
      float2 k2 = *(const float2*)&kn[s * HC + f];
      float2 v2 = *(const float2*)&vn[s * HC + f];
      float part = fmaf(q2.x, k2.x,
                   fmaf(q2.y, k2.y,
                   fmaf(p2.x, ea2.x, p2.y * ea2.y)));
#pragma unroll
      for (int off = 8; off > 0; off >>= 1) part += __shfl_xor(part, off, 64);
      float a = part * inv_sqrt;
      float nm = fmaxf(m, a);
      float sc = __expf(m - nm);
      float w = __expf(a - nm);
      m = nm;
      den = fmaf(den, sc, w);
      acc.x = fmaf(acc.x, sc, w * v2.x);
      acc.y = fmaf(acc.y, sc, w * v2.y);
      tac.x = fmaf(tac.x, sc, w * ea2.x);
      tac.y = fmaf(tac.y, sc, w * ea2.y);
    }
  }
  // fixup: (sum_e a_e * ea_e) @ we, per head
  __shared__ float tl[TPB][4 * 33];
  tl[wv_][h * 33 + dh] = tac.x;
  tl[wv_][h * 33 + dh + 1] = tac.y;
  // wave-private LDS region: no __syncthreads needed (compiler inserts lgkmcnt)
  float fx = 0.f, fy = 0.f;
  for (int j = 0; j < 32; ++j) {
    float tv = tl[wv_][h * 33 + j];
    fx = fmaf(tv, we[j * HC + f], fx);
    fy = fmaf(tv, we[j * HC + f + 1], fy);
  }
  float2 sk2 = *(const float2*)&sk[t * HC + f];
  float ox = 0.f, oy = 0.f;
  if (e1 > e0) {
    float rd = 1.0f / den;
    ox = (acc.x + fx) * rd;
    oy = (acc.y + fy) * rd;
  }
  ox += sk2.x;
  oy += sk2.y;
  ox = ox > 0.f ? ox : __expf(ox) - 1.f;   // ELU
  oy = oy > 0.f ? oy : __expf(oy) - 1.f;
  float2 o2 = {ox, oy};
  *(float2*)&out[t * HC + f] = o2;
}

// ---------------- global mean pool, parallel over node chunks ----------------
__global__ __launch_bounds__(128) void k_pool_sum(const float* __restrict__ h,
                                                  const int* __restrict__ batch,
                                                  float* __restrict__ psum) {
  int c = threadIdx.x;
  int n0 = blockIdx.x * PNB;
  int n1 = n0 + PNB;
  float acc = 0.f;
  int curb = batch[n0];             // wave-uniform
  for (int n = n0; n < n1; ++n) {
    int b = batch[n];
    if (b != curb) {
      atomicAdd(&psum[curb * HC + c], acc);
      acc = 0.f;
      curb = b;
    }
    acc += h[n * HC + c];
  }
  atomicAdd(&psum[curb * HC + c], acc);
}

// ---------------- classifier + log_softmax (division by count folded in) ----------------
__global__ __launch_bounds__(1024) void k_classify(const float* __restrict__ psum,
                                                   const int* __restrict__ batch,
                                                   const float* __restrict__ wlin,
                                                   const float* __restrict__ blin,
                                                   float* __restrict__ out) {
  int tid = threadIdx.x;           // 1024 = 64 graphs x 16 classes
  int b = tid >> 4, o = tid & 15;
  int lo = 0, hi = N_NODES;
  while (lo < hi) { int mid = (lo + hi) >> 1; if (batch[mid] < b) lo = mid + 1; else hi = mid; }
  int start = lo;
  lo = 0; hi = N_NODES;
  while (lo < hi) { int mid = (lo + hi) >> 1; if (batch[mid] <= b) lo = mid + 1; else hi = mid; }
  float cnt = fmaxf((float)(lo - start), 1.0f);
  float dot = 0.f;
  for (int d = 0; d < HC; ++d) dot = fmaf(psum[b * HC + d], wlin[d * OUT_C + o], dot);
  float acc = dot / cnt + blin[o];
  float mx = acc;
#pragma unroll
  for (int off = 8; off > 0; off >>= 1) mx = fmaxf(mx, __shfl_xor(mx, off, 64));
  float ex = __expf(acc - mx);
  float sum = ex;
#pragma unroll
  for (int off = 8; off > 0; off >>= 1) sum += __shfl_xor(sum, off, 64);
  out[tid] = acc - mx - logf(sum);
}

extern "C" void kernel_launch(void* const* d_in, const int* in_sizes, int n_in,
                              void* d_out, int out_size, void* d_ws, size_t ws_size,
                              hipStream_t stream) {
  const float* x = (const float*)d_in[0];
  const int* ei = (const int*)d_in[1];
  const float* ea = (const float*)d_in[2];
  const int* batch = (const int*)d_in[3];
  const float* wq1 = (const float*)d_in[4];  const float* bq1 = (const float*)d_in[5];
  const float* wk1 = (const float*)d_in[6];  const float* bk1 = (const float*)d_in[7];
  const float* wv1 = (const float*)d_in[8];  const float* bv1 = (const float*)d_in[9];
  const float* we1 = (const float*)d_in[10];
  const float* ws1 = (const float*)d_in[11]; const float* bs1 = (const float*)d_in[12];
  const float* wq2 = (const float*)d_in[13]; const float* bq2 = (const float*)d_in[14];
  const float* wk2 = (const float*)d_in[15]; const float* bk2 = (const float*)d_in[16];
  const float* wv2 = (const float*)d_in[17]; const float* bv2 = (const float*)d_in[18];
  const float* we2 = (const float*)d_in[19];
  const float* ws2 = (const float*)d_in[20]; const float* bs2 = (const float*)d_in[21];
  const float* wlin = (const float*)d_in[22]; const float* blin = (const float*)d_in[23];

  const int* srcI = ei;             // edge_index[0]
  const int* tgtI = ei + N_EDGES;   // edge_index[1]

  char* wsb = (char*)d_ws;
  size_t off = 0;
  auto alloc = [&](size_t bytes) -> void* {
    void* ptr = wsb + off;
    off += (bytes + 255) & ~(size_t)255;
    return ptr;
  };
  float* qn = (float*)alloc((size_t)N_NODES * HC * 4);
  float* kn = (float*)alloc((size_t)N_NODES * HC * 4);
  float* vn = (float*)alloc((size_t)N_NODES * HC * 4);
  float* sk = (float*)alloc((size_t)N_NODES * HC * 4);
  float* p  = (float*)alloc((size_t)N_NODES * HC * 4);
  float* h  = (float*)alloc((size_t)N_NODES * HC * 4);
  float* psum = (float*)alloc((size_t)NGRAPH * HC * 4);
  int* deg    = (int*)alloc((size_t)N_NODES * 4);
  int* offs   = (int*)alloc((size_t)(N_NODES + 1) * 4);
  int* cursor = (int*)alloc((size_t)N_NODES * 4);
  int* srcs   = (int*)alloc((size_t)N_EDGES * 4);
  int* eids   = (int*)alloc((size_t)N_EDGES * 4);

  // CSR build (shared by both layers)
  hipMemsetAsync(deg, 0, (size_t)N_NODES * 4, stream);
  k_hist<<<(N_EDGES + 255) / 256, 256, 0, stream>>>(tgtI, deg);
  k_scan<<<1, 1024, 0, stream>>>(deg, offs, cursor);
  k_scatter<<<(N_EDGES + 255) / 256, 256, 0, stream>>>(srcI, tgtI, cursor, srcs, eids);

  // Layer 1
  k_node_gemm<<<N_NODES / NPB, 128, 0, stream>>>(x, wq1, bq1, wk1, bk1, wv1, bv1,
                                                 ws1, bs1, we1, qn, kn, vn, sk, p);
  k_edge_attn<<<N_NODES / TPB, 64 * TPB, 0, stream>>>(offs, srcs, eids, ea, qn, kn, vn, sk, p, we1, h);

  // Layer 2
  k_node_gemm<<<N_NODES / NPB, 128, 0, stream>>>(h, wq2, bq2, wk2, bk2, wv2, bv2,
                                                 ws2, bs2, we2, qn, kn, vn, sk, p);
  k_edge_attn<<<N_NODES / TPB, 64 * TPB, 0, stream>>>(offs, srcs, eids, ea, qn, kn, vn, sk, p, we2, h);

  // Pool + classify
  hipMemsetAsync(psum, 0, (size_t)NGRAPH * HC * 4, stream);
  k_pool_sum<<<N_NODES / PNB, 128, 0, stream>>>(h, batch, psum);
  k_classify<<<1, 1024, 0, stream>>>(psum, batch, wlin, blin, (float*)d_out);
}

// Round 4
// 967.354 us; speedup vs baseline: 1.0004x; 1.0004x over previous
//
#include <hip/hip_runtime.h>

#define N_NODES 50000
#define N_EDGES 800000
#define IN_C 128
#define HID 32
#define HC 128
#define OUT_C 16
#define NGRAPH 64
#define NPB 8    // nodes per block in node GEMM
#define PNB 125  // nodes per block in pool (50000/125 = 400 blocks)
#define TPB 4    // targets per block in edge attn (4 waves of 64)

// ---------------- CSR build ----------------
__global__ void k_hist(const int* __restrict__ tgt, int* __restrict__ deg) {
  int i = blockIdx.x * blockDim.x + threadIdx.x;
  if (i < N_EDGES) atomicAdd(&deg[tgt[i]], 1);
}

// single-block scan, shfl-based
__global__ __launch_bounds__(1024) void k_scan(const int* __restrict__ deg,
                                               int* __restrict__ offs,
                                               int* __restrict__ cursor) {
  __shared__ int wsum[16];
  __shared__ int carry_s;
  int lane = threadIdx.x & 63, wid = threadIdx.x >> 6;
  if (threadIdx.x == 0) { carry_s = 0; offs[0] = 0; }
  __syncthreads();
  for (int base = 0; base < N_NODES; base += 1024) {
    int i = base + threadIdx.x;
    int v = (i < N_NODES) ? deg[i] : 0;
    int x = v;
#pragma unroll
    for (int off = 1; off < 64; off <<= 1) {
      int t = __shfl_up(x, off, 64);
      if (lane >= off) x += t;
    }
    if (lane == 63) wsum[wid] = x;
    __syncthreads();
    if (wid == 0 && lane < 16) {
      int s = wsum[lane];
#pragma unroll
      for (int off = 1; off < 16; off <<= 1) {
        int t = __shfl_up(s, off, 64);
        if (lane >= off) s += t;
      }
      wsum[lane] = s;
    }
    __syncthreads();
    int add = (wid > 0 ? wsum[wid - 1] : 0) + carry_s;
    int incl = x + add;
    if (i < N_NODES) { offs[i + 1] = incl; cursor[i] = incl - v; }
    __syncthreads();
    if (threadIdx.x == 1023) carry_s = incl;
    __syncthreads();
  }
}

__global__ void k_scatter(const int* __restrict__ src, const int* __restrict__ tgt,
                          int* __restrict__ cursor, int* __restrict__ srcs,
                          int* __restrict__ eids) {
  int i = blockIdx.x * blockDim.x + threadIdx.x;
  if (i < N_EDGES) {
    int pos = atomicAdd(&cursor[tgt[i]], 1);
    srcs[pos] = src[i];
    eids[pos] = i;
  }
}

// ---------------- node GEMM: qn/kn/vn/sk = x@W+b, plus p = f(qn, we) ----------------
__global__ __launch_bounds__(128) void k_node_gemm(
    const float* __restrict__ xin,
    const float* __restrict__ wq, const float* __restrict__ bq,
    const float* __restrict__ wk, const float* __restrict__ bk,
    const float* __restrict__ wv, const float* __restrict__ bv,
    const float* __restrict__ ws, const float* __restrict__ bs,
    const float* __restrict__ we,
    float* __restrict__ qn, float* __restrict__ kn, float* __restrict__ vn,
    float* __restrict__ sk, float* __restrict__ p) {
  int c = threadIdx.x;           // output column 0..127
  int n0 = blockIdx.x * NPB;
  float aq[NPB], ak[NPB], av[NPB], as_[NPB];
#pragma unroll
  for (int i = 0; i < NPB; ++i) { aq[i] = 0.f; ak[i] = 0.f; av[i] = 0.f; as_[i] = 0.f; }
  for (int d = 0; d < IN_C; ++d) {
    float wqv = wq[d * HC + c];
    float wkv = wk[d * HC + c];
    float wvv = wv[d * HC + c];
    float wsv = ws[d * HC + c];
#pragma unroll
    for (int i = 0; i < NPB; ++i) {
      float xv = xin[(n0 + i) * IN_C + d];   // wave-uniform -> scalar load
      aq[i] = fmaf(xv, wqv, aq[i]);
      ak[i] = fmaf(xv, wkv, ak[i]);
      av[i] = fmaf(xv, wvv, av[i]);
      as_[i] = fmaf(xv, wsv, as_[i]);
    }
  }
  __shared__ float qs[NPB][HC];
#pragma unroll
  for (int i = 0; i < NPB; ++i) {
    int n = n0 + i;
    float q = aq[i] + bq[c];
    qn[n * HC + c] = q;
    qs[i][c] = q;
    kn[n * HC + c] = ak[i] + bk[c];
    vn[n * HC + c] = av[i] + bv[c];
    sk[n * HC + c] = as_[i] + bs[c];
  }
  __syncthreads();
  int hb = (c >> 5) << 5;   // head base of column c
  int j = c & 31;
  float acc[NPB];
#pragma unroll
  for (int i = 0; i < NPB; ++i) acc[i] = 0.f;
  for (int d = 0; d < 32; ++d) {
    float wev = we[j * HC + hb + d];
#pragma unroll
    for (int i = 0; i < NPB; ++i) acc[i] = fmaf(qs[i][hb + d], wev, acc[i]);
  }
#pragma unroll
  for (int i = 0; i < NPB; ++i) p[(n0 + i) * HC + c] = acc[i];
}

// ---------------- edge attention ----------------
// 4 waves/block, one target per wave. Lane owns feature pair (2*lane, 2*lane+1);
// head = lane>>4. 4-way edge ILP: 4 independent online-softmax states, merged at end.
__global__ __launch_bounds__(256) void k_edge_attn(
    const int* __restrict__ offs, const int* __restrict__ srcs,
    const int* __restrict__ eids, const float* __restrict__ ea,
    const float* __restrict__ qn, const float* __restrict__ kn,
    const float* __restrict__ vn, const float* __restrict__ sk,
    const float* __restrict__ p, const float* __restrict__ we,
    float* __restrict__ out) {
  int lane = threadIdx.x & 63;
  int wv_ = threadIdx.x >> 6;
  int t = blockIdx.x * TPB + wv_;
  int f = 2 * lane;                 // feature pair base
  int h = lane >> 4;                // head of this lane
  int dh = 2 * (lane & 15);         // dim-pair within head (0..30)
  int e0 = offs[t], e1 = offs[t + 1];
  float2 q2 = *(const float2*)&qn[t * HC + f];
  float2 p2 = *(const float2*)&p[t * HC + f];
  const float inv_sqrt = 0.17677669529663687f;  // 1/sqrt(32)
  float m[4], den[4];
  float2 acc[4], tac[4];
#pragma unroll
  for (int u = 0; u < 4; ++u) {
    m[u] = -1e30f; den[u] = 0.f;
    acc[u].x = 0.f; acc[u].y = 0.f; tac[u].x = 0.f; tac[u].y = 0.f;
  }
  for (int base = e0; base < e1; base += 64) {
    int cnt = min(64, e1 - base);
    int li = base + lane;
    int sl = (li < e1) ? srcs[li] : 0;
    int el = (li < e1) ? eids[li] : 0;
    for (int jj = 0; jj < cnt; jj += 4) {
      float2 k2[4], v2[4], ea2[4];
      bool val[4];
#pragma unroll
      for (int u = 0; u < 4; ++u) {
        int j = jj + u;
        val[u] = (j < cnt);
        int jc = min(j, cnt - 1);
        int s = __shfl(sl, jc, 64);
        int eid = __shfl(el, jc, 64);
        k2[u] = *(const float2*)&kn[s * HC + f];
        v2[u] = *(const float2*)&vn[s * HC + f];
        ea2[u] = *(const float2*)&ea[eid * HID + dh];
      }
#pragma unroll
      for (int u = 0; u < 4; ++u) {
        float part = fmaf(q2.x, k2[u].x,
                     fmaf(q2.y, k2[u].y,
                     fmaf(p2.x, ea2[u].x, p2.y * ea2[u].y)));
#pragma unroll
        for (int off = 8; off > 0; off >>= 1) part += __shfl_xor(part, off, 64);
        float a = part * inv_sqrt;
        float nm = fmaxf(m[u], a);
        float sc = __expf(m[u] - nm);
        float w = val[u] ? __expf(a - nm) : 0.f;
        m[u] = nm;
        den[u] = fmaf(den[u], sc, w);
        acc[u].x = fmaf(acc[u].x, sc, w * v2[u].x);
        acc[u].y = fmaf(acc[u].y, sc, w * v2[u].y);
        tac[u].x = fmaf(tac[u].x, sc, w * ea2[u].x);
        tac[u].y = fmaf(tac[u].y, sc, w * ea2[u].y);
      }
    }
  }
  // merge the 4 slot-states
  float M = fmaxf(fmaxf(m[0], m[1]), fmaxf(m[2], m[3]));
  float dtot = 0.f;
  float2 A = {0.f, 0.f}, T = {0.f, 0.f};
#pragma unroll
  for (int u = 0; u < 4; ++u) {
    float sc = __expf(m[u] - M);   // m[u]=-1e30 (empty slot) -> sc=0
    dtot = fmaf(den[u], sc, dtot);
    A.x = fmaf(acc[u].x, sc, A.x);
    A.y = fmaf(acc[u].y, sc, A.y);
    T.x = fmaf(tac[u].x, sc, T.x);
    T.y = fmaf(tac[u].y, sc, T.y);
  }
  // fixup: (sum_e a_e * ea_e) @ we, per head
  __shared__ float tl[TPB][4 * 33];
  tl[wv_][h * 33 + dh] = T.x;
  tl[wv_][h * 33 + dh + 1] = T.y;
  // wave-private LDS region: no __syncthreads needed
  float fx = 0.f, fy = 0.f;
  for (int j = 0; j < 32; ++j) {
    float tv = tl[wv_][h * 33 + j];
    fx = fmaf(tv, we[j * HC + f], fx);
    fy = fmaf(tv, we[j * HC + f + 1], fy);
  }
  float2 sk2 = *(const float2*)&sk[t * HC + f];
  float ox = 0.f, oy = 0.f;
  if (e1 > e0) {
    float rd = 1.0f / dtot;
    ox = (A.x + fx) * rd;
    oy = (A.y + fy) * rd;
  }
  ox += sk2.x;
  oy += sk2.y;
  ox = ox > 0.f ? ox : __expf(ox) - 1.f;   // ELU
  oy = oy > 0.f ? oy : __expf(oy) - 1.f;
  float2 o2 = {ox, oy};
  *(float2*)&out[t * HC + f] = o2;
}

// ---------------- global mean pool, parallel over node chunks ----------------
__global__ __launch_bounds__(128) void k_pool_sum(const float* __restrict__ h,
                                                  const int* __restrict__ batch,
                                                  float* __restrict__ psum) {
  int c = threadIdx.x;
  int n0 = blockIdx.x * PNB;
  int n1 = n0 + PNB;
  float acc = 0.f;
  int curb = batch[n0];             // wave-uniform
  for (int n = n0; n < n1; ++n) {
    int b = batch[n];
    if (b != curb) {
      atomicAdd(&psum[curb * HC + c], acc);
      acc = 0.f;
      curb = b;
    }
    acc += h[n * HC + c];
  }
  atomicAdd(&psum[curb * HC + c], acc);
}

// ---------------- classifier + log_softmax (division by count folded in) ----------------
__global__ __launch_bounds__(1024) void k_classify(const float* __restrict__ psum,
                                                   const int* __restrict__ batch,
                                                   const float* __restrict__ wlin,
                                                   const float* __restrict__ blin,
                                                   float* __restrict__ out) {
  int tid = threadIdx.x;           // 1024 = 64 graphs x 16 classes
  int b = tid >> 4, o = tid & 15;
  int lo = 0, hi = N_NODES;
  while (lo < hi) { int mid = (lo + hi) >> 1; if (batch[mid] < b) lo = mid + 1; else hi = mid; }
  int start = lo;
  lo = 0; hi = N_NODES;
  while (lo < hi) { int mid = (lo + hi) >> 1; if (batch[mid] <= b) lo = mid + 1; else hi = mid; }
  float cnt = fmaxf((float)(lo - start), 1.0f);
  float dot = 0.f;
  for (int d = 0; d < HC; ++d) dot = fmaf(psum[b * HC + d], wlin[d * OUT_C + o], dot);
  float acc = dot / cnt + blin[o];
  float mx = acc;
#pragma unroll
  for (int off = 8; off > 0; off >>= 1) mx = fmaxf(mx, __shfl_xor(mx, off, 64));
  float ex = __expf(acc - mx);
  float sum = ex;
#pragma unroll
  for (int off = 8; off > 0; off >>= 1) sum += __shfl_xor(sum, off, 64);
  out[tid] = acc - mx - logf(sum);
}

extern "C" void kernel_launch(void* const* d_in, const int* in_sizes, int n_in,
                              void* d_out, int out_size, void* d_ws, size_t ws_size,
                              hipStream_t stream) {
  const float* x = (const float*)d_in[0];
  const int* ei = (const int*)d_in[1];
  const float* ea = (const float*)d_in[2];
  const int* batch = (const int*)d_in[3];
  const float* wq1 = (const float*)d_in[4];  const float* bq1 = (const float*)d_in[5];
  const float* wk1 = (const float*)d_in[6];  const float* bk1 = (const float*)d_in[7];
  const float* wv1 = (const float*)d_in[8];  const float* bv1 = (const float*)d_in[9];
  const float* we1 = (const float*)d_in[10];
  const float* ws1 = (const float*)d_in[11]; const float* bs1 = (const float*)d_in[12];
  const float* wq2 = (const float*)d_in[13]; const float* bq2 = (const float*)d_in[14];
  const float* wk2 = (const float*)d_in[15]; const float* bk2 = (const float*)d_in[16];
  const float* wv2 = (const float*)d_in[17]; const float* bv2 = (const float*)d_in[18];
  const float* we2 = (const float*)d_in[19];
  const float* ws2 = (const float*)d_in[20]; const float* bs2 = (const float*)d_in[21];
  const float* wlin = (const float*)d_in[22]; const float* blin = (const float*)d_in[23];

  const int* srcI = ei;             // edge_index[0]
  const int* tgtI = ei + N_EDGES;   // edge_index[1]

  char* wsb = (char*)d_ws;
  size_t off = 0;
  auto alloc = [&](size_t bytes) -> void* {
    void* ptr = wsb + off;
    off += (bytes + 255) & ~(size_t)255;
    return ptr;
  };
  float* qn = (float*)alloc((size_t)N_NODES * HC * 4);
  float* kn = (float*)alloc((size_t)N_NODES * HC * 4);
  float* vn = (float*)alloc((size_t)N_NODES * HC * 4);
  float* sk = (float*)alloc((size_t)N_NODES * HC * 4);
  float* p  = (float*)alloc((size_t)N_NODES * HC * 4);
  float* h  = (float*)alloc((size_t)N_NODES * HC * 4);
  float* psum = (float*)alloc((size_t)NGRAPH * HC * 4);
  int* deg    = (int*)alloc((size_t)N_NODES * 4);
  int* offs   = (int*)alloc((size_t)(N_NODES + 1) * 4);
  int* cursor = (int*)alloc((size_t)N_NODES * 4);
  int* srcs   = (int*)alloc((size_t)N_EDGES * 4);
  int* eids   = (int*)alloc((size_t)N_EDGES * 4);

  // CSR build (shared by both layers)
  hipMemsetAsync(deg, 0, (size_t)N_NODES * 4, stream);
  k_hist<<<(N_EDGES + 255) / 256, 256, 0, stream>>>(tgtI, deg);
  k_scan<<<1, 1024, 0, stream>>>(deg, offs, cursor);
  k_scatter<<<(N_EDGES + 255) / 256, 256, 0, stream>>>(srcI, tgtI, cursor, srcs, eids);

  // Layer 1
  k_node_gemm<<<N_NODES / NPB, 128, 0, stream>>>(x, wq1, bq1, wk1, bk1, wv1, bv1,
                                                 ws1, bs1, we1, qn, kn, vn, sk, p);
  k_edge_attn<<<N_NODES / TPB, 64 * TPB, 0, stream>>>(offs, srcs, eids, ea, qn, kn, vn, sk, p, we1, h);

  // Layer 2
  k_node_gemm<<<N_NODES / NPB, 128, 0, stream>>>(h, wq2, bq2, wk2, bk2, wv2, bv2,
                                                 ws2, bs2, we2, qn, kn, vn, sk, p);
  k_edge_attn<<<N_NODES / TPB, 64 * TPB, 0, stream>>>(offs, srcs, eids, ea, qn, kn, vn, sk, p, we2, h);

  // Pool + classify
  hipMemsetAsync(psum, 0, (size_t)NGRAPH * HC * 4, stream);
  k_pool_sum<<<N_NODES / PNB, 128, 0, stream>>>(h, batch, psum);
  k_classify<<<1, 1024, 0, stream>>>(psum, batch, wlin, blin, (float*)d_out);
}

// Round 5
// 912.863 us; speedup vs baseline: 1.0601x; 1.0597x over previous
//
#include <hip/hip_runtime.h>

#define N_NODES 50000
#define N_EDGES 800000
#define IN_C 128
#define HID 32
#define HC 128
#define OUT_C 16
#define NGRAPH 64
#define NPB 8    // nodes per block in node GEMM
#define PNB 125  // nodes per block in pool (50000/125 = 400 blocks)
#define TPB 4    // targets per block in edge attn (4 waves of 64)

// ---------------- CSR build ----------------
__global__ void k_hist(const int* __restrict__ tgt, int* __restrict__ deg) {
  int i = blockIdx.x * blockDim.x + threadIdx.x;
  if (i < N_EDGES) atomicAdd(&deg[tgt[i]], 1);
}

// single-block scan, shfl-based
__global__ __launch_bounds__(1024) void k_scan(const int* __restrict__ deg,
                                               int* __restrict__ offs,
                                               int* __restrict__ cursor) {
  __shared__ int wsum[16];
  __shared__ int carry_s;
  int lane = threadIdx.x & 63, wid = threadIdx.x >> 6;
  if (threadIdx.x == 0) { carry_s = 0; offs[0] = 0; }
  __syncthreads();
  for (int base = 0; base < N_NODES; base += 1024) {
    int i = base + threadIdx.x;
    int v = (i < N_NODES) ? deg[i] : 0;
    int x = v;
#pragma unroll
    for (int off = 1; off < 64; off <<= 1) {
      int t = __shfl_up(x, off, 64);
      if (lane >= off) x += t;
    }
    if (lane == 63) wsum[wid] = x;
    __syncthreads();
    if (wid == 0 && lane < 16) {
      int s = wsum[lane];
#pragma unroll
      for (int off = 1; off < 16; off <<= 1) {
        int t = __shfl_up(s, off, 64);
        if (lane >= off) s += t;
      }
      wsum[lane] = s;
    }
    __syncthreads();
    int add = (wid > 0 ? wsum[wid - 1] : 0) + carry_s;
    int incl = x + add;
    if (i < N_NODES) { offs[i + 1] = incl; cursor[i] = incl - v; }
    __syncthreads();
    if (threadIdx.x == 1023) carry_s = incl;
    __syncthreads();
  }
}

__global__ void k_scatter(const int* __restrict__ src, const int* __restrict__ tgt,
                          int* __restrict__ cursor, int* __restrict__ srcs,
                          int* __restrict__ eids) {
  int i = blockIdx.x * blockDim.x + threadIdx.x;
  if (i < N_EDGES) {
    int pos = atomicAdd(&cursor[tgt[i]], 1);
    srcs[pos] = src[i];
    eids[pos] = i;
  }
}

// ---------------- node GEMM: qn/kn/vn/sk = x@W+b, plus p = f(qn, we) ----------------
__global__ __launch_bounds__(128) void k_node_gemm(
    const float* __restrict__ xin,
    const float* __restrict__ wq, const float* __restrict__ bq,
    const float* __restrict__ wk, const float* __restrict__ bk,
    const float* __restrict__ wv, const float* __restrict__ bv,
    const float* __restrict__ ws, const float* __restrict__ bs,
    const float* __restrict__ we,
    float* __restrict__ qn, float* __restrict__ kn, float* __restrict__ vn,
    float* __restrict__ sk, float* __restrict__ p) {
  int c = threadIdx.x;           // output column 0..127
  int n0 = blockIdx.x * NPB;
  float aq[NPB], ak[NPB], av[NPB], as_[NPB];
#pragma unroll
  for (int i = 0; i < NPB; ++i) { aq[i] = 0.f; ak[i] = 0.f; av[i] = 0.f; as_[i] = 0.f; }
  for (int d = 0; d < IN_C; ++d) {
    float wqv = wq[d * HC + c];
    float wkv = wk[d * HC + c];
    float wvv = wv[d * HC + c];
    float wsv = ws[d * HC + c];
#pragma unroll
    for (int i = 0; i < NPB; ++i) {
      float xv = xin[(n0 + i) * IN_C + d];   // wave-uniform -> scalar load
      aq[i] = fmaf(xv, wqv, aq[i]);
      ak[i] = fmaf(xv, wkv, ak[i]);
      av[i] = fmaf(xv, wvv, av[i]);
      as_[i] = fmaf(xv, wsv, as_[i]);
    }
  }
  __shared__ float qs[NPB][HC];
#pragma unroll
  for (int i = 0; i < NPB; ++i) {
    int n = n0 + i;
    float q = aq[i] + bq[c];
    qn[n * HC + c] = q;
    qs[i][c] = q;
    kn[n * HC + c] = ak[i] + bk[c];
    vn[n * HC + c] = av[i] + bv[c];
    sk[n * HC + c] = as_[i] + bs[c];
  }
  __syncthreads();
  int hb = (c >> 5) << 5;   // head base of column c
  int j = c & 31;
  float acc[NPB];
#pragma unroll
  for (int i = 0; i < NPB; ++i) acc[i] = 0.f;
  for (int d = 0; d < 32; ++d) {
    float wev = we[j * HC + hb + d];
#pragma unroll
    for (int i = 0; i < NPB; ++i) acc[i] = fmaf(qs[i][hb + d], wev, acc[i]);
  }
#pragma unroll
  for (int i = 0; i < NPB; ++i) p[(n0 + i) * HC + c] = acc[i];
}

// ---------------- edge attention ----------------
// 4 waves/block, one target per wave. 2 edges per iteration: lanes 0-31 = edge A,
// lanes 32-63 = edge B. Lane owns 4 features (float4); head = 8-lane group,
// dot-reduce = 3 shfl_xor steps. Two online-softmax states merged at the end.
__global__ __launch_bounds__(256) void k_edge_attn(
    const int* __restrict__ offs, const int* __restrict__ srcs,
    const int* __restrict__ eids, const float* __restrict__ ea,
    const float* __restrict__ qn, const float* __restrict__ kn,
    const float* __restrict__ vn, const float* __restrict__ sk,
    const float* __restrict__ p, const float* __restrict__ we,
    float* __restrict__ out) {
  int lane = threadIdx.x & 63;
  int wv_ = threadIdx.x >> 6;
  int t = blockIdx.x * TPB + wv_;
  int l32 = lane & 31;
  int half = lane >> 5;
  int f = 4 * l32;                // feature base (0..124); also = head*32 + 4*g
  int g = l32 & 7;                // lane-in-head-group (0..7)
  int ed = 4 * g;                 // ea-dim base (0..28)
  int h = l32 >> 3;               // head (0..3)
  int e0 = offs[t], e1 = offs[t + 1];
  float4 q4 = *(const float4*)&qn[t * HC + f];
  float4 p4 = *(const float4*)&p[t * HC + f];
  const float inv_sqrt = 0.17677669529663687f;  // 1/sqrt(32)
  float m = -1e30f, den = 0.f;
  float4 acc = {0.f, 0.f, 0.f, 0.f}, tac = {0.f, 0.f, 0.f, 0.f};
  for (int base = e0; base < e1; base += 64) {
    int cnt = min(64, e1 - base);
    int li = base + lane;
    int sl = (li < e1) ? srcs[li] : 0;
    int el = (li < e1) ? eids[li] : 0;
    for (int jj = 0; jj < cnt; jj += 2) {
      int j = jj + half;
      bool val = (j < cnt);
      int jc = min(j, cnt - 1);
      int s = __shfl(sl, jc, 64);
      int eid = __shfl(el, jc, 64);
      float4 k4 = *(const float4*)&kn[s * HC + f];
      float4 v4 = *(const float4*)&vn[s * HC + f];
      float4 e4 = *(const float4*)&ea[eid * HID + ed];
      float part = fmaf(q4.x, k4.x, fmaf(q4.y, k4.y,
                   fmaf(q4.z, k4.z, fmaf(q4.w, k4.w,
                   fmaf(p4.x, e4.x, fmaf(p4.y, e4.y,
                   fmaf(p4.z, e4.z, p4.w * e4.w)))))));
      part += __shfl_xor(part, 1, 64);
      part += __shfl_xor(part, 2, 64);
      part += __shfl_xor(part, 4, 64);
      float a = part * inv_sqrt;
      float nm = fmaxf(m, a);
      float sc = __expf(m - nm);
      float w = val ? __expf(a - nm) : 0.f;
      m = nm;
      den = fmaf(den, sc, w);
      acc.x = fmaf(acc.x, sc, w * v4.x);
      acc.y = fmaf(acc.y, sc, w * v4.y);
      acc.z = fmaf(acc.z, sc, w * v4.z);
      acc.w = fmaf(acc.w, sc, w * v4.w);
      tac.x = fmaf(tac.x, sc, w * e4.x);
      tac.y = fmaf(tac.y, sc, w * e4.y);
      tac.z = fmaf(tac.z, sc, w * e4.z);
      tac.w = fmaf(tac.w, sc, w * e4.w);
    }
  }
  // merge the two half-states (both halves end with identical merged values)
  float m_o = __shfl_xor(m, 32, 64);
  float M = fmaxf(m, m_o);
  float s_s = __expf(m - M), s_o = __expf(m_o - M);
  float den_o = __shfl_xor(den, 32, 64);
  float dtot = fmaf(den, s_s, den_o * s_o);
  float4 A, T;
  A.x = fmaf(acc.x, s_s, __shfl_xor(acc.x, 32, 64) * s_o);
  A.y = fmaf(acc.y, s_s, __shfl_xor(acc.y, 32, 64) * s_o);
  A.z = fmaf(acc.z, s_s, __shfl_xor(acc.z, 32, 64) * s_o);
  A.w = fmaf(acc.w, s_s, __shfl_xor(acc.w, 32, 64) * s_o);
  T.x = fmaf(tac.x, s_s, __shfl_xor(tac.x, 32, 64) * s_o);
  T.y = fmaf(tac.y, s_s, __shfl_xor(tac.y, 32, 64) * s_o);
  T.z = fmaf(tac.z, s_s, __shfl_xor(tac.z, 32, 64) * s_o);
  T.w = fmaf(tac.w, s_s, __shfl_xor(tac.w, 32, 64) * s_o);
  // fixup: (sum_e a_e * ea_e) @ we, per head
  __shared__ float tl[TPB][HC];
  if (half == 0) *(float4*)&tl[wv_][f] = T;   // lanes 0-31 cover all 4 heads
  // wave-private LDS region: compiler inserts lgkmcnt waits, no barrier needed
  float4 fx = {0.f, 0.f, 0.f, 0.f};
  for (int j = 0; j < 32; ++j) {
    float tv = tl[wv_][h * 32 + j];
    float4 w4 = *(const float4*)&we[j * HC + f];
    fx.x = fmaf(tv, w4.x, fx.x);
    fx.y = fmaf(tv, w4.y, fx.y);
    fx.z = fmaf(tv, w4.z, fx.z);
    fx.w = fmaf(tv, w4.w, fx.w);
  }
  float4 sk4 = *(const float4*)&sk[t * HC + f];
  float4 o;
  float rd = (e1 > e0) ? (1.0f / dtot) : 0.f;
  o.x = (A.x + fx.x) * rd + sk4.x;
  o.y = (A.y + fx.y) * rd + sk4.y;
  o.z = (A.z + fx.z) * rd + sk4.z;
  o.w = (A.w + fx.w) * rd + sk4.w;
  o.x = o.x > 0.f ? o.x : __expf(o.x) - 1.f;   // ELU
  o.y = o.y > 0.f ? o.y : __expf(o.y) - 1.f;
  o.z = o.z > 0.f ? o.z : __expf(o.z) - 1.f;
  o.w = o.w > 0.f ? o.w : __expf(o.w) - 1.f;
  if (half == 0) *(float4*)&out[t * HC + f] = o;
}

// ---------------- global mean pool, parallel over node chunks ----------------
__global__ __launch_bounds__(128) void k_pool_sum(const float* __restrict__ h,
                                                  const int* __restrict__ batch,
                                                  float* __restrict__ psum) {
  int c = threadIdx.x;
  int n0 = blockIdx.x * PNB;
  int n1 = n0 + PNB;
  float acc = 0.f;
  int curb = batch[n0];             // wave-uniform
  for (int n = n0; n < n1; ++n) {
    int b = batch[n];
    if (b != curb) {
      atomicAdd(&psum[curb * HC + c], acc);
      acc = 0.f;
      curb = b;
    }
    acc += h[n * HC + c];
  }
  atomicAdd(&psum[curb * HC + c], acc);
}

// ---------------- classifier + log_softmax (division by count folded in) ----------------
__global__ __launch_bounds__(1024) void k_classify(const float* __restrict__ psum,
                                                   const int* __restrict__ batch,
                                                   const float* __restrict__ wlin,
                                                   const float* __restrict__ blin,
                                                   float* __restrict__ out) {
  int tid = threadIdx.x;           // 1024 = 64 graphs x 16 classes
  int b = tid >> 4, o = tid & 15;
  int lo = 0, hi = N_NODES;
  while (lo < hi) { int mid = (lo + hi) >> 1; if (batch[mid] < b) lo = mid + 1; else hi = mid; }
  int start = lo;
  lo = 0; hi = N_NODES;
  while (lo < hi) { int mid = (lo + hi) >> 1; if (batch[mid] <= b) lo = mid + 1; else hi = mid; }
  float cnt = fmaxf((float)(lo - start), 1.0f);
  float dot = 0.f;
  for (int d = 0; d < HC; ++d) dot = fmaf(psum[b * HC + d], wlin[d * OUT_C + o], dot);
  float acc = dot / cnt + blin[o];
  float mx = acc;
#pragma unroll
  for (int off = 8; off > 0; off >>= 1) mx = fmaxf(mx, __shfl_xor(mx, off, 64));
  float ex = __expf(acc - mx);
  float sum = ex;
#pragma unroll
  for (int off = 8; off > 0; off >>= 1) sum += __shfl_xor(sum, off, 64);
  out[tid] = acc - mx - logf(sum);
}

extern "C" void kernel_launch(void* const* d_in, const int* in_sizes, int n_in,
                              void* d_out, int out_size, void* d_ws, size_t ws_size,
                              hipStream_t stream) {
  const float* x = (const float*)d_in[0];
  const int* ei = (const int*)d_in[1];
  const float* ea = (const float*)d_in[2];
  const int* batch = (const int*)d_in[3];
  const float* wq1 = (const float*)d_in[4];  const float* bq1 = (const float*)d_in[5];
  const float* wk1 = (const float*)d_in[6];  const float* bk1 = (const float*)d_in[7];
  const float* wv1 = (const float*)d_in[8];  const float* bv1 = (const float*)d_in[9];
  const float* we1 = (const float*)d_in[10];
  const float* ws1 = (const float*)d_in[11]; const float* bs1 = (const float*)d_in[12];
  const float* wq2 = (const float*)d_in[13]; const float* bq2 = (const float*)d_in[14];
  const float* wk2 = (const float*)d_in[15]; const float* bk2 = (const float*)d_in[16];
  const float* wv2 = (const float*)d_in[17]; const float* bv2 = (const float*)d_in[18];
  const float* we2 = (const float*)d_in[19];
  const float* ws2 = (const float*)d_in[20]; const float* bs2 = (const float*)d_in[21];
  const float* wlin = (const float*)d_in[22]; const float* blin = (const float*)d_in[23];

  const int* srcI = ei;             // edge_index[0]
  const int* tgtI = ei + N_EDGES;   // edge_index[1]

  char* wsb = (char*)d_ws;
  size_t off = 0;
  auto alloc = [&](size_t bytes) -> void* {
    void* ptr = wsb + off;
    off += (bytes + 255) & ~(size_t)255;
    return ptr;
  };
  float* qn = (float*)alloc((size_t)N_NODES * HC * 4);
  float* kn = (float*)alloc((size_t)N_NODES * HC * 4);
  float* vn = (float*)alloc((size_t)N_NODES * HC * 4);
  float* sk = (float*)alloc((size_t)N_NODES * HC * 4);
  float* p  = (float*)alloc((size_t)N_NODES * HC * 4);
  float* h  = (float*)alloc((size_t)N_NODES * HC * 4);
  float* psum = (float*)alloc((size_t)NGRAPH * HC * 4);
  int* deg    = (int*)alloc((size_t)N_NODES * 4);
  int* offs   = (int*)alloc((size_t)(N_NODES + 1) * 4);
  int* cursor = (int*)alloc((size_t)N_NODES * 4);
  int* srcs   = (int*)alloc((size_t)N_EDGES * 4);
  int* eids   = (int*)alloc((size_t)N_EDGES * 4);

  // CSR build (shared by both layers)
  hipMemsetAsync(deg, 0, (size_t)N_NODES * 4, stream);
  k_hist<<<(N_EDGES + 255) / 256, 256, 0, stream>>>(tgtI, deg);
  k_scan<<<1, 1024, 0, stream>>>(deg, offs, cursor);
  k_scatter<<<(N_EDGES + 255) / 256, 256, 0, stream>>>(srcI, tgtI, cursor, srcs, eids);

  // Layer 1
  k_node_gemm<<<N_NODES / NPB, 128, 0, stream>>>(x, wq1, bq1, wk1, bk1, wv1, bv1,
                                                 ws1, bs1, we1, qn, kn, vn, sk, p);
  k_edge_attn<<<N_NODES / TPB, 64 * TPB, 0, stream>>>(offs, srcs, eids, ea, qn, kn, vn, sk, p, we1, h);

  // Layer 2
  k_node_gemm<<<N_NODES / NPB, 128, 0, stream>>>(h, wq2, bq2, wk2, bk2, wv2, bv2,
                                                 ws2, bs2, we2, qn, kn, vn, sk, p);
  k_edge_attn<<<N_NODES / TPB, 64 * TPB, 0, stream>>>(offs, srcs, eids, ea, qn, kn, vn, sk, p, we2, h);

  // Pool + classify
  hipMemsetAsync(psum, 0, (size_t)NGRAPH * HC * 4, stream);
  k_pool_sum<<<N_NODES / PNB, 128, 0, stream>>>(h, batch, psum);
  k_classify<<<1, 1024, 0, stream>>>(psum, batch, wlin, blin, (float*)d_out);
}